// Round 11
// baseline (705.254 us; speedup 1.0000x reference)
//
#include <hip/hip_runtime.h>
#include <math.h>

#define D 512
#define HEADS 8
#define NLAYER 6
#define LSEQ 1024
#define BATCH 4
#define DKH 64
#define MTOK (BATCH*LSEQ)   // 4096 tokens
#define EPS 1e-5f
#define EMB_SCALE 22.627416997969522f  // sqrt(512)
#define INV_SCALE 0.125f               // 1/sqrt(64)

typedef __attribute__((ext_vector_type(8))) __bf16 bf16x8;
typedef __attribute__((ext_vector_type(4))) float f32x4;

__device__ __forceinline__ unsigned short f2bf(float x) {
    union { float f; unsigned u; } v; v.f = x;
    unsigned r = (v.u + 0x7FFFu + ((v.u >> 16) & 1u)) >> 16;
    return (unsigned short)r;
}
__device__ __forceinline__ unsigned pack2(float a, float b) {
    return (unsigned)f2bf(a) | ((unsigned)f2bf(b) << 16);
}
__device__ __forceinline__ void gl_lds16(const unsigned short* g, unsigned short* l) {
    __builtin_amdgcn_global_load_lds(
        (const __attribute__((address_space(1))) unsigned*)g,
        (__attribute__((address_space(3))) unsigned*)l, 16, 0, 0);
}
// asm 16B global load (attn): volatile asm cannot be sunk -> pipeline holds.
__device__ __forceinline__ void gload16(bf16x8& d, const unsigned short* p) {
    asm volatile("global_load_dwordx4 %0, %1, off" : "=v"(d) : "v"(p));
}

// ---------------- prep: ALL-layer weight fp32->bf16 + biases + embedding ----
__global__ __launch_bounds__(256) void prep_kernel(
    const int* __restrict__ tokens, const float* __restrict__ emb,
    const float* __restrict__ Wq, const float* __restrict__ Wkv,
    const float* __restrict__ Wo, const float* __restrict__ W1,
    const float* __restrict__ W2, const float* __restrict__ bq,
    const float* __restrict__ bkv, unsigned short* __restrict__ wl,
    float* __restrict__ wbias, float* __restrict__ x)
{
    const int bid = blockIdx.x;
    if (bid < 9216) {                       // weight conversion, 6 layers
        const int l = bid / 1536;
        const int e = (bid - l * 1536) * 2048 + threadIdx.x * 8;
        const float* src;
        if      (e < 262144)  src = Wq  + (size_t)l * 262144  + e;
        else if (e < 786432)  src = Wkv + (size_t)l * 524288  + (e - 262144);
        else if (e < 1048576) src = Wo  + (size_t)l * 262144  + (e - 786432);
        else if (e < 2097152) src = W1  + (size_t)l * 1048576 + (e - 1048576);
        else                  src = W2  + (size_t)l * 1048576 + (e - 2097152);
        float4 a = *(const float4*)src;
        float4 b = *(const float4*)(src + 4);
        uint4 o;
        o.x = pack2(a.x, a.y); o.y = pack2(a.z, a.w);
        o.z = pack2(b.x, b.y); o.w = pack2(b.z, b.w);
        *(uint4*)(wl + (size_t)l * 3145728 + e) = o;
    } else if (bid == 9216) {               // combined QKV biases, 6 layers
        for (int i = threadIdx.x; i < 9216; i += 256) {
            int l = i / 1536, j = i - l * 1536;
            wbias[i] = (j < 512) ? bq[l * 512 + j] : bkv[l * 1024 + (j - 512)];
        }
    } else {                                // embedding + positional encoding
        int row = (bid - 9217) * 2 + (threadIdx.x >> 7);
        int pos = row & (LSEQ - 1);
        int tok = tokens[row];
        int c = (threadIdx.x & 127) * 4;
        float4 e = *(const float4*)(emb + (size_t)tok * D + c);
        float o[4] = {e.x, e.y, e.z, e.w};
#pragma unroll
        for (int i = 0; i < 4; ++i) {
            int col = c + i;
            int ii = col & ~1;
            float dv = expf(-(float)ii * (9.210340371976184f / (float)D));
            float a = (float)pos * dv;
            float pe = (col & 1) ? cosf(a) : sinf(a);
            o[i] = o[i] * EMB_SCALE + pe;
        }
        float4 r; r.x = o[0]; r.y = o[1]; r.z = o[2]; r.w = o[3];
        *(float4*)(x + (size_t)row * D + c) = r;
    }
}

// ---------------- layernorm fp32 -> bf16: one wave per row ----------------
__global__ __launch_bounds__(256) void ln_kernel(
    const float* __restrict__ x, const float* __restrict__ g,
    const float* __restrict__ b, unsigned short* __restrict__ h)
{
    int lane = threadIdx.x & 63;
    int row = blockIdx.x * 4 + (threadIdx.x >> 6);
    const float* xr = x + (size_t)row * D + lane * 8;
    float4 v0 = *(const float4*)(xr);
    float4 v1 = *(const float4*)(xr + 4);
    float s = v0.x + v0.y + v0.z + v0.w + v1.x + v1.y + v1.z + v1.w;
#pragma unroll
    for (int off = 32; off; off >>= 1) s += __shfl_xor(s, off, 64);
    float m = s * (1.0f / D);
    float d0 = v0.x - m, d1 = v0.y - m, d2 = v0.z - m, d3 = v0.w - m;
    float d4 = v1.x - m, d5 = v1.y - m, d6 = v1.z - m, d7 = v1.w - m;
    float ss = d0*d0 + d1*d1 + d2*d2 + d3*d3 + d4*d4 + d5*d5 + d6*d6 + d7*d7;
#pragma unroll
    for (int off = 32; off; off >>= 1) ss += __shfl_xor(ss, off, 64);
    float inv = rsqrtf(ss * (1.0f / D) + EPS);
    const float* gp = g + lane * 8;
    const float* bp = b + lane * 8;
    float4 g0 = *(const float4*)(gp), g1 = *(const float4*)(gp + 4);
    float4 b0 = *(const float4*)(bp), b1 = *(const float4*)(bp + 4);
    uint4 o;
    o.x = pack2(d0 * inv * g0.x + b0.x, d1 * inv * g0.y + b0.y);
    o.y = pack2(d2 * inv * g0.z + b0.z, d3 * inv * g0.w + b0.w);
    o.z = pack2(d4 * inv * g1.x + b1.x, d5 * inv * g1.y + b1.y);
    o.w = pack2(d6 * inv * g1.z + b1.z, d7 * inv * g1.w + b1.w);
    *(uint4*)(h + (size_t)row * D + lane * 8) = o;
}

// ---------------- bf16 MFMA GEMM: acc = A(bf16 MxK) @ W(bf16 NxK)^T ----------------
// 2-phase double-buffered pipeline, XOR-swizzled LDS (R3/R4/R9/R10 validated).
// R11: FFN1 also moves BN 128->64 (same occupancy lever as R9/R10: 1024
// blocks = 4/CU, 3 resident at 48KB LDS, was 2).
// OMODE 0: C fp32 [M][N] = acc + bias + X (residual)
// OMODE 1: C bf16 [M][N] = relu(acc + bias)
// OMODE 2: fused QKV (N=1536), fragment-linear outputs for attn.
template<int OMODE, int BM, int BN, int BK>
__global__ __launch_bounds__(256) void gemm_bf16(
    const unsigned short* __restrict__ A, const unsigned short* __restrict__ W,
    const float* __restrict__ bias, const float* __restrict__ X,
    void* __restrict__ C, void* __restrict__ C2, void* __restrict__ C3,
    int M, int N, int K)
{
    constexpr int WM = BM / 64;        // 2 or 1
    constexpr int WN = 4 / WM;         // 2 or 4
    constexpr int NI = BN / (WN * 16); // 16-col frags per wave
    constexpr int CPB = BK / 8;        // 8-short chunks per row
    constexpr int RPP = 2048 / BK;     // rows covered per 256-thread pass
    __shared__ __align__(16) unsigned short As[2][BM * BK];
    __shared__ __align__(16) unsigned short Bs[2][BN * BK];
    const int tid = threadIdx.x;
    const int wave = tid >> 6, lane = tid & 63;
    const int quad = lane >> 4, l16 = lane & 15;
    const int wm = wave / WN, wn = wave % WN;
    const int bm = blockIdx.y * BM, bn = blockIdx.x * BN;

    // staging: thread covers row rS of each RPP-row group, chunk ch (8 shorts).
    // source column chunk is XOR-swizzled so linear LDS holds swizzled data:
    // LDS[r][c] = G[r][c ^ (r&7)]; reads apply the same XOR.
    const int rS  = tid / CPB;
    const int ch  = tid % CPB;
    const int csw = ((ch ^ (rS & 7)) << 3);
    const unsigned short* Asrc = A + (size_t)(bm + rS) * K + csw;
    const unsigned short* Bsrc = W + (size_t)(bn + rS) * K + csw;

    f32x4 acc[4][NI];
#pragma unroll
    for (int mi = 0; mi < 4; ++mi)
#pragma unroll
        for (int ni = 0; ni < NI; ++ni) acc[mi][ni] = (f32x4){0.f, 0.f, 0.f, 0.f};

    const int nt = K / BK;

    // prologue: stage tile 0
#pragma unroll
    for (int i = 0; i < BM / RPP; ++i)
        gl_lds16(Asrc + (size_t)(i * RPP) * K, &As[0][i * 2048 + tid * 8]);
#pragma unroll
    for (int i = 0; i < BN / RPP; ++i)
        gl_lds16(Bsrc + (size_t)(i * RPP) * K, &Bs[0][i * 2048 + tid * 8]);
    __syncthreads();

    for (int t = 0; t < nt; ++t) {
        const int cur = t & 1;
        if (t + 1 < nt) {
            const int k0 = (t + 1) * BK;
#pragma unroll
            for (int i = 0; i < BM / RPP; ++i)
                gl_lds16(Asrc + (size_t)(i * RPP) * K + k0, &As[cur ^ 1][i * 2048 + tid * 8]);
#pragma unroll
            for (int i = 0; i < BN / RPP; ++i)
                gl_lds16(Bsrc + (size_t)(i * RPP) * K + k0, &Bs[cur ^ 1][i * 2048 + tid * 8]);
        }
#pragma unroll
        for (int kc = 0; kc < BK / 32; ++kc) {
            const int gch = (kc << 2) | quad;   // global col chunk this quad wants
            bf16x8 af[4], bfr[NI];
#pragma unroll
            for (int mi = 0; mi < 4; ++mi) {
                const int ra = wm * 64 + mi * 16 + l16;
                af[mi] = *(const bf16x8*)&As[cur][ra * BK + ((gch ^ (ra & 7)) << 3)];
            }
#pragma unroll
            for (int ni = 0; ni < NI; ++ni) {
                const int rb = wn * (BN / WN) + ni * 16 + l16;
                bfr[ni] = *(const bf16x8*)&Bs[cur][rb * BK + ((gch ^ (rb & 7)) << 3)];
            }
#pragma unroll
            for (int mi = 0; mi < 4; ++mi)
#pragma unroll
                for (int ni = 0; ni < NI; ++ni)
                    acc[mi][ni] = __builtin_amdgcn_mfma_f32_16x16x32_bf16(
                        af[mi], bfr[ni], acc[mi][ni], 0, 0, 0);
        }
        __syncthreads();   // drains vmcnt(0): next tile landed, cur reads done
    }

    const int er = bm + wm * 64;
    const int ec = bn + wn * (BN / WN);

    if (OMODE == 0) {
        float* Cf = (float*)C;
#pragma unroll
        for (int ni = 0; ni < NI; ++ni) {
            int c = ec + ni * 16 + l16;
            float bv = bias[c];
#pragma unroll
            for (int mi = 0; mi < 4; ++mi)
#pragma unroll
                for (int r = 0; r < 4; ++r) {
                    int m = er + mi * 16 + quad * 4 + r;
                    Cf[(size_t)m * N + c] = acc[mi][ni][r] + bv + X[(size_t)m * N + c];
                }
        }
    } else if (OMODE == 1) {
        unsigned short* Cb = (unsigned short*)C;
#pragma unroll
        for (int ni = 0; ni < NI; ++ni) {
            int c = ec + ni * 16 + l16;
            float bv = bias[c];
#pragma unroll
            for (int mi = 0; mi < 4; ++mi)
#pragma unroll
                for (int r = 0; r < 4; ++r) {
                    int m = er + mi * 16 + quad * 4 + r;
                    Cb[(size_t)m * N + c] = f2bf(fmaxf(acc[mi][ni][r] + bv, 0.f));
                }
        }
    } else {
        if (bn < 512) {            // Q (scaled), fragment-linear
            unsigned short* Qp = (unsigned short*)C;
#pragma unroll
            for (int ni = 0; ni < NI; ++ni) {
                int c = ec + ni * 16 + l16;
                float bv = bias[c];
                int hh = c >> 6, dd = c & 63;
                size_t cbase = (size_t)(dd >> 5) * 512 + (size_t)((dd >> 3) & 3) * 128 + (dd & 7);
#pragma unroll
                for (int mi = 0; mi < 4; ++mi)
#pragma unroll
                    for (int r = 0; r < 4; ++r) {
                        int m = er + mi * 16 + quad * 4 + r;
                        int b = m >> 10, t = m & 1023;
                        Qp[(size_t)(b * 8 + hh) * 65536 + (size_t)(t >> 4) * 1024
                           + cbase + (size_t)(t & 15) * 8] =
                            f2bf((acc[mi][ni][r] + bv) * INV_SCALE);
                    }
            }
        } else if (bn < 1024) {    // K, fragment-linear
            unsigned short* Kp = (unsigned short*)C2;
#pragma unroll
            for (int ni = 0; ni < NI; ++ni) {
                int c = ec + ni * 16 + l16;
                float bv = bias[c];
                int c2 = c - 512;
                int hh = c2 >> 6, dd = c2 & 63;
                size_t cbase = (size_t)(dd >> 5) * 512 + (size_t)((dd >> 3) & 3) * 128 + (dd & 7);
#pragma unroll
                for (int mi = 0; mi < 4; ++mi)
#pragma unroll
                    for (int r = 0; r < 4; ++r) {
                        int m = er + mi * 16 + quad * 4 + r;
                        int b = m >> 10, t = m & 1023;
                        Kp[(size_t)(b * 8 + hh) * 65536 + (size_t)(t >> 4) * 1024
                           + cbase + (size_t)(t & 15) * 8] =
                            f2bf(acc[mi][ni][r] + bv);
                    }
            }
        } else {                   // V, fragment-linear (transposed consumption)
            unsigned short* Vp = (unsigned short*)C3;
#pragma unroll
            for (int ni = 0; ni < NI; ++ni) {
                int c = ec + ni * 16 + l16;
                float bv = bias[c];
                int c2 = c - 1024;
                int hh = c2 >> 6, dd = c2 & 63;
                size_t dbase = (size_t)(dd >> 4) * 16384 + (size_t)(dd & 15) * 8;
#pragma unroll
                for (int mi = 0; mi < 4; ++mi) {
                    int t0 = er + mi * 16 + quad * 4;
                    int b = t0 >> 10, tt = t0 & 1023;
                    ushort4 o;
                    o.x = f2bf(acc[mi][ni][0] + bv);
                    o.y = f2bf(acc[mi][ni][1] + bv);
                    o.z = f2bf(acc[mi][ni][2] + bv);
                    o.w = f2bf(acc[mi][ni][3] + bv);
                    *(ushort4*)(Vp + (size_t)(b * 8 + hh) * 65536 + dbase
                                + (size_t)(tt >> 5) * 512
                                + (size_t)((tt >> 3) & 3) * 128 + (tt & 7)) = o;
                }
            }
        }
    }
}

// ---------------- flash attention: split-K, QROWS=32, 32-key pipeline ----
// R11: key-tile 64 -> 32 (8 iters). R10's VGPR_Count=120 proved the 64-key
// double-buffer (176 live VGPRs needed) was serialized by regalloc -> the
// "pipeline" ran partially sequential (MfmaUtil 6.7%). 32-key tiles halve
// the buffer state (kc[2][4]+vf[2][4] = 64 VGPR, total live ~140) so the
// double-buffer actually materializes. Per 32-key iter: 8 loads, 8 QK^T
// MFMAs, one f-transform per qs (validated f0 path; 32-key P fragment pairs
// 1:1 with V key-chunk), 8 PV MFMAs. Counted vmcnt(8) keeps next tile in
// flight. Fragment-linear layouts (R2) unchanged.
__global__ __launch_bounds__(256, 1) void attn_mfma(
    const unsigned short* __restrict__ Qb, const unsigned short* __restrict__ Kb,
    const unsigned short* __restrict__ Vt, unsigned short* __restrict__ av)
{
    __shared__ float Ol[4][32][68];   // [wave][q][d] fp32 partial O (+pad)
    __shared__ float Ls[4][32];       // [wave][q] partial denominators
    const int tid = threadIdx.x;
    const int wave = tid >> 6, lane = tid & 63;
    const int quad = lane >> 4, l16 = lane & 15;
    const int bh = blockIdx.x & 31;          // xcd = bh % 8 -> K/V L2-resident per XCD
    const int b = bh >> 3, h = bh & 7;
    const int q0 = (blockIdx.x >> 5) * 32;   // 32 q-tiles of 32 rows

    const unsigned short* qp = Qb + (size_t)bh * 65536 + (size_t)(q0 >> 4) * 1024 + lane * 8;
    const unsigned short* kbase = Kb + (size_t)bh * 65536 + lane * 8;
    const unsigned short* vbase = Vt + (size_t)bh * 65536 + lane * 8;

    // bpermute byte addresses: pull from quad (2q)&3 / (2q+1)&3 at same l16
    const int sA  = ((((2 * quad) & 3) << 4) + l16) << 2;
    const int sB2 = ((((2 * quad + 1) & 3) << 4) + l16) << 2;

    f32x4 o[2][4];
#pragma unroll
    for (int qs = 0; qs < 2; ++qs)
#pragma unroll
        for (int nf = 0; nf < 4; ++nf) o[qs][nf] = (f32x4){0.f, 0.f, 0.f, 0.f};
    float lp[2] = {0.f, 0.f};   // per-lane partial column (=query) sums

    const int j0 = wave * 256;

    // ---- prologue: issue Q (4) + buffer0 K/V (8) loads; 12 in flight ----
    bf16x8 qf[2][2];
    gload16(qf[0][0], qp);
    gload16(qf[0][1], qp + 512);
    gload16(qf[1][0], qp + 1024);
    gload16(qf[1][1], qp + 1536);

    bf16x8 kc[2][4], vf[2][4];
    gload16(kc[0][0], kbase + (size_t)j0 * 64);
    gload16(kc[0][1], kbase + (size_t)j0 * 64 + 512);
    gload16(kc[0][2], kbase + (size_t)j0 * 64 + 1024);
    gload16(kc[0][3], kbase + (size_t)j0 * 64 + 1536);
#pragma unroll
    for (int nf = 0; nf < 4; ++nf)
        gload16(vf[0][nf], vbase + (size_t)j0 * 16 + nf * 16384);

#pragma unroll
    for (int it = 0; it < 8; ++it) {
        const int cur = it & 1, nxt = cur ^ 1;
        // ---- issue next 32-key tile's 8 loads BEFORE waiting on current ----
        if (it < 7) {
            const int jn = j0 + (it + 1) * 32;
            gload16(kc[nxt][0], kbase + (size_t)jn * 64);
            gload16(kc[nxt][1], kbase + (size_t)jn * 64 + 512);
            gload16(kc[nxt][2], kbase + (size_t)jn * 64 + 1024);
            gload16(kc[nxt][3], kbase + (size_t)jn * 64 + 1536);
#pragma unroll
            for (int nf = 0; nf < 4; ++nf)
                gload16(vf[nxt][nf], vbase + (size_t)jn * 16 + nf * 16384);
        }
        // ---- counted wait: current tile (+Q at it=0) done, next 8 in flight ----
        if (it < 7) asm volatile("s_waitcnt vmcnt(8)" ::: "memory");
        else        asm volatile("s_waitcnt vmcnt(0)" ::: "memory");
        __builtin_amdgcn_sched_barrier(0);
        // ---- S^T sub-tiles (row=key, col=query), exp, pack — per (nf, qs) ----
        unsigned pk01[2][2], pk23[2][2];
#pragma unroll
        for (int nf = 0; nf < 2; ++nf)
#pragma unroll
            for (int qs = 0; qs < 2; ++qs) {
                f32x4 z = {0.f, 0.f, 0.f, 0.f};
                z = __builtin_amdgcn_mfma_f32_16x16x32_bf16(kc[cur][2 * nf], qf[qs][0], z, 0, 0, 0);
                z = __builtin_amdgcn_mfma_f32_16x16x32_bf16(kc[cur][2 * nf + 1], qf[qs][1], z, 0, 0, 0);
                float p0 = __expf(z[0]);
                float p1 = __expf(z[1]);
                float p2 = __expf(z[2]);
                float p3 = __expf(z[3]);
                lp[qs] += (p0 + p1) + (p2 + p3);
                pk01[qs][nf] = pack2(p0, p1);
                pk23[qs][nf] = pack2(p2, p3);
            }
        // ---- register-only C->A transform (validated f0 path), per qs ----
#pragma unroll
        for (int qs = 0; qs < 2; ++qs) {
            union PU { unsigned d[4]; bf16x8 v; } f0;
            unsigned a0, a1;
            a0 = (unsigned)__builtin_amdgcn_ds_bpermute(sA,  (int)pk01[qs][0]);
            a1 = (unsigned)__builtin_amdgcn_ds_bpermute(sA,  (int)pk01[qs][1]);
            f0.d[0] = (quad < 2) ? a0 : a1;
            a0 = (unsigned)__builtin_amdgcn_ds_bpermute(sA,  (int)pk23[qs][0]);
            a1 = (unsigned)__builtin_amdgcn_ds_bpermute(sA,  (int)pk23[qs][1]);
            f0.d[1] = (quad < 2) ? a0 : a1;
            a0 = (unsigned)__builtin_amdgcn_ds_bpermute(sB2, (int)pk01[qs][0]);
            a1 = (unsigned)__builtin_amdgcn_ds_bpermute(sB2, (int)pk01[qs][1]);
            f0.d[2] = (quad < 2) ? a0 : a1;
            a0 = (unsigned)__builtin_amdgcn_ds_bpermute(sB2, (int)pk23[qs][0]);
            a1 = (unsigned)__builtin_amdgcn_ds_bpermute(sB2, (int)pk23[qs][1]);
            f0.d[3] = (quad < 2) ? a0 : a1;
            // ---- O += P.V (one 32-key MFMA per d-tile) ----
#pragma unroll
            for (int nf = 0; nf < 4; ++nf)
                o[qs][nf] = __builtin_amdgcn_mfma_f32_16x16x32_bf16(
                    f0.v, vf[cur][nf], o[qs][nf], 0, 0, 0);
        }
    }
    // ---- write per-wave partials to LDS ----
#pragma unroll
    for (int qs = 0; qs < 2; ++qs)
#pragma unroll
        for (int nf = 0; nf < 4; ++nf)
#pragma unroll
            for (int r = 0; r < 4; ++r)
                Ol[wave][qs * 16 + quad * 4 + r][nf * 16 + l16] = o[qs][nf][r];
#pragma unroll
    for (int qs = 0; qs < 2; ++qs) {
        float ts = lp[qs];
        ts += __shfl_xor(ts, 16, 64);
        ts += __shfl_xor(ts, 32, 64);
        if (quad == 0) Ls[wave][qs * 16 + l16] = ts;
    }
    __syncthreads();
    // ---- combine: wave w handles d-frag nf=w, 32 q rows ----
#pragma unroll
    for (int half = 0; half < 2; ++half)
#pragma unroll
        for (int r = 0; r < 4; ++r) {
            int qq = half * 16 + quad * 4 + r;
            float denom = Ls[0][qq] + Ls[1][qq] + Ls[2][qq] + Ls[3][qq];
            float v = Ol[0][qq][wave * 16 + l16] + Ol[1][qq][wave * 16 + l16]
                    + Ol[2][qq][wave * 16 + l16] + Ol[3][qq][wave * 16 + l16];
            int q = q0 + qq;
            av[((size_t)(b * 1024 + q)) * D + h * 64 + wave * 16 + l16] =
                f2bf(v / denom);
        }
}

// ---------------- classifier ----------------
__global__ __launch_bounds__(256) void cls_kernel(
    const float* __restrict__ x, const float* __restrict__ Wc,
    const float* __restrict__ bc, float* __restrict__ out)
{
    int lane = threadIdx.x & 63;
    int row = blockIdx.x * 4 + (threadIdx.x >> 6);
    const float* xr = x + (size_t)row * D + lane * 8;
    float4 v0 = *(const float4*)xr;
    float4 v1 = *(const float4*)(xr + 4);
    float acc[10];
#pragma unroll
    for (int c = 0; c < 10; ++c) {
        const float* wr = Wc + c * D + lane * 8;
        float4 w0 = *(const float4*)wr;
        float4 w1 = *(const float4*)(wr + 4);
        acc[c] = v0.x*w0.x + v0.y*w0.y + v0.z*w0.z + v0.w*w0.w
               + v1.x*w1.x + v1.y*w1.y + v1.z*w1.z + v1.w*w1.w;
    }
#pragma unroll
    for (int c = 0; c < 10; ++c)
#pragma unroll
        for (int off = 32; off; off >>= 1) acc[c] += __shfl_xor(acc[c], off, 64);
    if (lane == 0) {
#pragma unroll
        for (int c = 0; c < 10; ++c) out[(size_t)row * 10 + c] = acc[c] + bc[c];
    }
}

extern "C" void kernel_launch(void* const* d_in, const int* in_sizes, int n_in,
                              void* d_out, int out_size, void* d_ws, size_t ws_size,
                              hipStream_t stream)
{
    const int*   tokens = (const int*)  d_in[0];
    const float* emb    = (const float*)d_in[1];
    const float* Wq     = (const float*)d_in[2];
    const float* bq     = (const float*)d_in[3];
    const float* Wkv    = (const float*)d_in[4];
    const float* bkv    = (const float*)d_in[5];
    const float* Wo     = (const float*)d_in[6];
    const float* bo     = (const float*)d_in[7];
    const float* ln1g   = (const float*)d_in[8];
    const float* ln1b   = (const float*)d_in[9];
    const float* W1     = (const float*)d_in[10];
    const float* b1     = (const float*)d_in[11];
    const float* W2     = (const float*)d_in[12];
    const float* b2     = (const float*)d_in[13];
    const float* ln2g   = (const float*)d_in[14];
    const float* ln2b   = (const float*)d_in[15];
    const float* Wc     = (const float*)d_in[16];
    const float* bc     = (const float*)d_in[17];
    float* out = (float*)d_out;

    // workspace (~64 MB; harness poisons >=268MB per fillBuffer WRITE_SIZE):
    // x fp32 8MB | hb bf16 4MB | Qb 4 | Kb 4 | Vt 4 | avb 4 (f1b aliases Qb..)
    // | wl bf16 6x6MB = 36MB | wbias fp32 36KB
    float* x  = (float*)d_ws;
    unsigned short* hb  = (unsigned short*)(x + (size_t)MTOK * D);
    unsigned short* Qb  = hb  + (size_t)MTOK * D;
    unsigned short* Kb  = Qb  + (size_t)32 * 1024 * 64;
    unsigned short* Vt  = Kb  + (size_t)32 * 1024 * 64;
    unsigned short* avb = Vt  + (size_t)32 * 1024 * 64;
    unsigned short* f1b = Qb;                              // [4096][2048] bf16 = 16 MB
    unsigned short* wl  = avb + (size_t)32 * 1024 * 64;    // all-layer bf16 weights (36 MB)
    float* wbias = (float*)(wl + (size_t)6 * 3145728);     // combined [bq;bkv] x 6 (36 KB)

    // per-layer wl layout: [Wq;Wkv] contiguous 1536x512, then Wo, W1, W2
    const size_t oWo = 786432, oW1 = 1048576, oW2 = 2097152, LW = 3145728;

    prep_kernel<<<11265, 256, 0, stream>>>(
        tokens, emb, Wq, Wkv, Wo, W1, W2, bq, bkv, wl, wbias, x);

    for (int l = 0; l < NLAYER; ++l) {
        const unsigned short* wll = wl + (size_t)l * LW;
        ln_kernel<<<MTOK / 4, 256, 0, stream>>>(x, ln1g + l * D, ln1b + l * D, hb);
        gemm_bf16<2,128,64,64><<<dim3(24, 32), 256, 0, stream>>>(
            hb, wll, wbias + l * 1536, nullptr, Qb, Kb, Vt, MTOK, 1536, 512);
        attn_mfma<<<1024, 256, 0, stream>>>(Qb, Kb, Vt, avb);
        gemm_bf16<0,64,64,128><<<dim3(8, 64), 256, 0, stream>>>(
            avb, wll + oWo, bo + l * D, x, x, nullptr, nullptr, MTOK, D, D);
        ln_kernel<<<MTOK / 4, 256, 0, stream>>>(x, ln2g + l * D, ln2b + l * D, hb);
        gemm_bf16<1,128,64,64><<<dim3(32, 32), 256, 0, stream>>>(
            hb, wll + oW1, b1 + l * 4 * D, nullptr, f1b, nullptr, nullptr, MTOK, 4 * D, D);
        gemm_bf16<0,64,64,128><<<dim3(8, 64), 256, 0, stream>>>(
            f1b, wll + oW2, b2 + l * D, x, x, nullptr, nullptr, MTOK, D, 4 * D);
    }

    cls_kernel<<<MTOK / 4, 256, 0, stream>>>(x, Wc, bc, out);
}

// Round 12
// 687.622 us; speedup vs baseline: 1.0256x; 1.0256x over previous
//
#include <hip/hip_runtime.h>
#include <math.h>

#define D 512
#define HEADS 8
#define NLAYER 6
#define LSEQ 1024
#define BATCH 4
#define DKH 64
#define MTOK (BATCH*LSEQ)   // 4096 tokens
#define EPS 1e-5f
#define EMB_SCALE 22.627416997969522f  // sqrt(512)
#define INV_SCALE 0.125f               // 1/sqrt(64)

typedef __attribute__((ext_vector_type(8))) __bf16 bf16x8;
typedef __attribute__((ext_vector_type(4))) float f32x4;

__device__ __forceinline__ unsigned short f2bf(float x) {
    union { float f; unsigned u; } v; v.f = x;
    unsigned r = (v.u + 0x7FFFu + ((v.u >> 16) & 1u)) >> 16;
    return (unsigned short)r;
}
__device__ __forceinline__ unsigned pack2(float a, float b) {
    return (unsigned)f2bf(a) | ((unsigned)f2bf(b) << 16);
}
__device__ __forceinline__ void gl_lds16(const unsigned short* g, unsigned short* l) {
    __builtin_amdgcn_global_load_lds(
        (const __attribute__((address_space(1))) unsigned*)g,
        (__attribute__((address_space(3))) unsigned*)l, 16, 0, 0);
}

// ---------------- prep: ALL-layer weight fp32->bf16 + biases + embedding ----
__global__ __launch_bounds__(256) void prep_kernel(
    const int* __restrict__ tokens, const float* __restrict__ emb,
    const float* __restrict__ Wq, const float* __restrict__ Wkv,
    const float* __restrict__ Wo, const float* __restrict__ W1,
    const float* __restrict__ W2, const float* __restrict__ bq,
    const float* __restrict__ bkv, unsigned short* __restrict__ wl,
    float* __restrict__ wbias, float* __restrict__ x)
{
    const int bid = blockIdx.x;
    if (bid < 9216) {                       // weight conversion, 6 layers
        const int l = bid / 1536;
        const int e = (bid - l * 1536) * 2048 + threadIdx.x * 8;
        const float* src;
        if      (e < 262144)  src = Wq  + (size_t)l * 262144  + e;
        else if (e < 786432)  src = Wkv + (size_t)l * 524288  + (e - 262144);
        else if (e < 1048576) src = Wo  + (size_t)l * 262144  + (e - 786432);
        else if (e < 2097152) src = W1  + (size_t)l * 1048576 + (e - 1048576);
        else                  src = W2  + (size_t)l * 1048576 + (e - 2097152);
        float4 a = *(const float4*)src;
        float4 b = *(const float4*)(src + 4);
        uint4 o;
        o.x = pack2(a.x, a.y); o.y = pack2(a.z, a.w);
        o.z = pack2(b.x, b.y); o.w = pack2(b.z, b.w);
        *(uint4*)(wl + (size_t)l * 3145728 + e) = o;
    } else if (bid == 9216) {               // combined QKV biases, 6 layers
        for (int i = threadIdx.x; i < 9216; i += 256) {
            int l = i / 1536, j = i - l * 1536;
            wbias[i] = (j < 512) ? bq[l * 512 + j] : bkv[l * 1024 + (j - 512)];
        }
    } else {                                // embedding + positional encoding
        int row = (bid - 9217) * 2 + (threadIdx.x >> 7);
        int pos = row & (LSEQ - 1);
        int tok = tokens[row];
        int c = (threadIdx.x & 127) * 4;
        float4 e = *(const float4*)(emb + (size_t)tok * D + c);
        float o[4] = {e.x, e.y, e.z, e.w};
#pragma unroll
        for (int i = 0; i < 4; ++i) {
            int col = c + i;
            int ii = col & ~1;
            float dv = expf(-(float)ii * (9.210340371976184f / (float)D));
            float a = (float)pos * dv;
            float pe = (col & 1) ? cosf(a) : sinf(a);
            o[i] = o[i] * EMB_SCALE + pe;
        }
        float4 r; r.x = o[0]; r.y = o[1]; r.z = o[2]; r.w = o[3];
        *(float4*)(x + (size_t)row * D + c) = r;
    }
}

// ---------------- layernorm fp32 -> bf16: one wave per row ----------------
__global__ __launch_bounds__(256) void ln_kernel(
    const float* __restrict__ x, const float* __restrict__ g,
    const float* __restrict__ b, unsigned short* __restrict__ h)
{
    int lane = threadIdx.x & 63;
    int row = blockIdx.x * 4 + (threadIdx.x >> 6);
    const float* xr = x + (size_t)row * D + lane * 8;
    float4 v0 = *(const float4*)(xr);
    float4 v1 = *(const float4*)(xr + 4);
    float s = v0.x + v0.y + v0.z + v0.w + v1.x + v1.y + v1.z + v1.w;
#pragma unroll
    for (int off = 32; off; off >>= 1) s += __shfl_xor(s, off, 64);
    float m = s * (1.0f / D);
    float d0 = v0.x - m, d1 = v0.y - m, d2 = v0.z - m, d3 = v0.w - m;
    float d4 = v1.x - m, d5 = v1.y - m, d6 = v1.z - m, d7 = v1.w - m;
    float ss = d0*d0 + d1*d1 + d2*d2 + d3*d3 + d4*d4 + d5*d5 + d6*d6 + d7*d7;
#pragma unroll
    for (int off = 32; off; off >>= 1) ss += __shfl_xor(ss, off, 64);
    float inv = rsqrtf(ss * (1.0f / D) + EPS);
    const float* gp = g + lane * 8;
    const float* bp = b + lane * 8;
    float4 g0 = *(const float4*)(gp), g1 = *(const float4*)(gp + 4);
    float4 b0 = *(const float4*)(bp), b1 = *(const float4*)(bp + 4);
    uint4 o;
    o.x = pack2(d0 * inv * g0.x + b0.x, d1 * inv * g0.y + b0.y);
    o.y = pack2(d2 * inv * g0.z + b0.z, d3 * inv * g0.w + b0.w);
    o.z = pack2(d4 * inv * g1.x + b1.x, d5 * inv * g1.y + b1.y);
    o.w = pack2(d6 * inv * g1.z + b1.z, d7 * inv * g1.w + b1.w);
    *(uint4*)(h + (size_t)row * D + lane * 8) = o;
}

// ---------------- bf16 MFMA GEMM: acc = A(bf16 MxK) @ W(bf16 NxK)^T ----------------
// 2-phase double-buffered pipeline, XOR-swizzled LDS. R10 measured-best
// config restored (R11's FFN1 BN=64 was part of a regression -> reverted):
// QKV BN=64 (768 blocks = 3/CU), Wo/FFN2 BM=64 BN=64 BK=128 (512 = 2/CU),
// FFN1 BM=128 BN=128 BK=64.
// OMODE 0: C fp32 [M][N] = acc + bias + X (residual)
// OMODE 1: C bf16 [M][N] = relu(acc + bias)
// OMODE 2: fused QKV (N=1536), fragment-linear outputs for attn.
template<int OMODE, int BM, int BN, int BK>
__global__ __launch_bounds__(256) void gemm_bf16(
    const unsigned short* __restrict__ A, const unsigned short* __restrict__ W,
    const float* __restrict__ bias, const float* __restrict__ X,
    void* __restrict__ C, void* __restrict__ C2, void* __restrict__ C3,
    int M, int N, int K)
{
    constexpr int WM = BM / 64;        // 2 or 1
    constexpr int WN = 4 / WM;         // 2 or 4
    constexpr int NI = BN / (WN * 16); // 16-col frags per wave
    constexpr int CPB = BK / 8;        // 8-short chunks per row
    constexpr int RPP = 2048 / BK;     // rows covered per 256-thread pass
    __shared__ __align__(16) unsigned short As[2][BM * BK];
    __shared__ __align__(16) unsigned short Bs[2][BN * BK];
    const int tid = threadIdx.x;
    const int wave = tid >> 6, lane = tid & 63;
    const int quad = lane >> 4, l16 = lane & 15;
    const int wm = wave / WN, wn = wave % WN;
    const int bm = blockIdx.y * BM, bn = blockIdx.x * BN;

    // staging: thread covers row rS of each RPP-row group, chunk ch (8 shorts).
    // source column chunk is XOR-swizzled so linear LDS holds swizzled data:
    // LDS[r][c] = G[r][c ^ (r&7)]; reads apply the same XOR.
    const int rS  = tid / CPB;
    const int ch  = tid % CPB;
    const int csw = ((ch ^ (rS & 7)) << 3);
    const unsigned short* Asrc = A + (size_t)(bm + rS) * K + csw;
    const unsigned short* Bsrc = W + (size_t)(bn + rS) * K + csw;

    f32x4 acc[4][NI];
#pragma unroll
    for (int mi = 0; mi < 4; ++mi)
#pragma unroll
        for (int ni = 0; ni < NI; ++ni) acc[mi][ni] = (f32x4){0.f, 0.f, 0.f, 0.f};

    const int nt = K / BK;

    // prologue: stage tile 0
#pragma unroll
    for (int i = 0; i < BM / RPP; ++i)
        gl_lds16(Asrc + (size_t)(i * RPP) * K, &As[0][i * 2048 + tid * 8]);
#pragma unroll
    for (int i = 0; i < BN / RPP; ++i)
        gl_lds16(Bsrc + (size_t)(i * RPP) * K, &Bs[0][i * 2048 + tid * 8]);
    __syncthreads();

    for (int t = 0; t < nt; ++t) {
        const int cur = t & 1;
        if (t + 1 < nt) {
            const int k0 = (t + 1) * BK;
#pragma unroll
            for (int i = 0; i < BM / RPP; ++i)
                gl_lds16(Asrc + (size_t)(i * RPP) * K + k0, &As[cur ^ 1][i * 2048 + tid * 8]);
#pragma unroll
            for (int i = 0; i < BN / RPP; ++i)
                gl_lds16(Bsrc + (size_t)(i * RPP) * K + k0, &Bs[cur ^ 1][i * 2048 + tid * 8]);
        }
#pragma unroll
        for (int kc = 0; kc < BK / 32; ++kc) {
            const int gch = (kc << 2) | quad;   // global col chunk this quad wants
            bf16x8 af[4], bfr[NI];
#pragma unroll
            for (int mi = 0; mi < 4; ++mi) {
                const int ra = wm * 64 + mi * 16 + l16;
                af[mi] = *(const bf16x8*)&As[cur][ra * BK + ((gch ^ (ra & 7)) << 3)];
            }
#pragma unroll
            for (int ni = 0; ni < NI; ++ni) {
                const int rb = wn * (BN / WN) + ni * 16 + l16;
                bfr[ni] = *(const bf16x8*)&Bs[cur][rb * BK + ((gch ^ (rb & 7)) << 3)];
            }
#pragma unroll
            for (int mi = 0; mi < 4; ++mi)
#pragma unroll
                for (int ni = 0; ni < NI; ++ni)
                    acc[mi][ni] = __builtin_amdgcn_mfma_f32_16x16x32_bf16(
                        af[mi], bfr[ni], acc[mi][ni], 0, 0, 0);
        }
        __syncthreads();   // drains vmcnt(0): next tile landed, cur reads done
    }

    const int er = bm + wm * 64;
    const int ec = bn + wn * (BN / WN);

    if (OMODE == 0) {
        float* Cf = (float*)C;
#pragma unroll
        for (int ni = 0; ni < NI; ++ni) {
            int c = ec + ni * 16 + l16;
            float bv = bias[c];
#pragma unroll
            for (int mi = 0; mi < 4; ++mi)
#pragma unroll
                for (int r = 0; r < 4; ++r) {
                    int m = er + mi * 16 + quad * 4 + r;
                    Cf[(size_t)m * N + c] = acc[mi][ni][r] + bv + X[(size_t)m * N + c];
                }
        }
    } else if (OMODE == 1) {
        unsigned short* Cb = (unsigned short*)C;
#pragma unroll
        for (int ni = 0; ni < NI; ++ni) {
            int c = ec + ni * 16 + l16;
            float bv = bias[c];
#pragma unroll
            for (int mi = 0; mi < 4; ++mi)
#pragma unroll
                for (int r = 0; r < 4; ++r) {
                    int m = er + mi * 16 + quad * 4 + r;
                    Cb[(size_t)m * N + c] = f2bf(fmaxf(acc[mi][ni][r] + bv, 0.f));
                }
        }
    } else {
        if (bn < 512) {            // Q (scaled), fragment-linear
            unsigned short* Qp = (unsigned short*)C;
#pragma unroll
            for (int ni = 0; ni < NI; ++ni) {
                int c = ec + ni * 16 + l16;
                float bv = bias[c];
                int hh = c >> 6, dd = c & 63;
                size_t cbase = (size_t)(dd >> 5) * 512 + (size_t)((dd >> 3) & 3) * 128 + (dd & 7);
#pragma unroll
                for (int mi = 0; mi < 4; ++mi)
#pragma unroll
                    for (int r = 0; r < 4; ++r) {
                        int m = er + mi * 16 + quad * 4 + r;
                        int b = m >> 10, t = m & 1023;
                        Qp[(size_t)(b * 8 + hh) * 65536 + (size_t)(t >> 4) * 1024
                           + cbase + (size_t)(t & 15) * 8] =
                            f2bf((acc[mi][ni][r] + bv) * INV_SCALE);
                    }
            }
        } else if (bn < 1024) {    // K, fragment-linear
            unsigned short* Kp = (unsigned short*)C2;
#pragma unroll
            for (int ni = 0; ni < NI; ++ni) {
                int c = ec + ni * 16 + l16;
                float bv = bias[c];
                int c2 = c - 512;
                int hh = c2 >> 6, dd = c2 & 63;
                size_t cbase = (size_t)(dd >> 5) * 512 + (size_t)((dd >> 3) & 3) * 128 + (dd & 7);
#pragma unroll
                for (int mi = 0; mi < 4; ++mi)
#pragma unroll
                    for (int r = 0; r < 4; ++r) {
                        int m = er + mi * 16 + quad * 4 + r;
                        int b = m >> 10, t = m & 1023;
                        Kp[(size_t)(b * 8 + hh) * 65536 + (size_t)(t >> 4) * 1024
                           + cbase + (size_t)(t & 15) * 8] =
                            f2bf(acc[mi][ni][r] + bv);
                    }
            }
        } else {                   // V, fragment-linear (transposed consumption)
            unsigned short* Vp = (unsigned short*)C3;
#pragma unroll
            for (int ni = 0; ni < NI; ++ni) {
                int c = ec + ni * 16 + l16;
                float bv = bias[c];
                int c2 = c - 1024;
                int hh = c2 >> 6, dd = c2 & 63;
                size_t dbase = (size_t)(dd >> 4) * 16384 + (size_t)(dd & 15) * 8;
#pragma unroll
                for (int mi = 0; mi < 4; ++mi) {
                    int t0 = er + mi * 16 + quad * 4;
                    int b = t0 >> 10, tt = t0 & 1023;
                    ushort4 o;
                    o.x = f2bf(acc[mi][ni][0] + bv);
                    o.y = f2bf(acc[mi][ni][1] + bv);
                    o.z = f2bf(acc[mi][ni][2] + bv);
                    o.w = f2bf(acc[mi][ni][3] + bv);
                    *(ushort4*)(Vp + (size_t)(b * 8 + hh) * 65536 + dbase
                                + (size_t)(tt >> 5) * 512
                                + (size_t)((tt >> 3) & 3) * 128 + (tt & 7)) = o;
                }
            }
        }
    }
}

// ---------------- flash attention: LDS-shared K/V, 64 q-rows/block ----------------
// R12: the register-double-buffer attn (R4 structure) proved regalloc-
// UNSTABLE across builds (rule #19): identical source measured ~27us in
// R4-R9 builds but 42.5us/VGPR=120 in R10, and R11's smaller quantum
// regressed further. This LDS variant (validated R6, measured == good-build
// private attn) has a small stable register footprint: K/V tiles staged once
// per block via global_load_lds into double-buffered LDS, shared by 4 waves;
// the proven 2-phase barrier loop handles sync. Wave w owns q-rows
// [w*16, w*16+16) over the full 1024-key sweep; no split-K combine.
__global__ __launch_bounds__(256, 2) void attn_mfma(
    const unsigned short* __restrict__ Qb, const unsigned short* __restrict__ Kb,
    const unsigned short* __restrict__ Vt, unsigned short* __restrict__ av)
{
    __shared__ __align__(16) unsigned short Ks[2][4096];
    __shared__ __align__(16) unsigned short Vs[2][4096];
    const int tid = threadIdx.x;
    const int wave = tid >> 6, lane = tid & 63;
    const int quad = lane >> 4, l16 = lane & 15;
    const int bh = blockIdx.x & 31;          // xcd = bh % 8 -> K/V L2-resident per XCD
    const int b = bh >> 3, h = bh & 7;
    const int q0 = (blockIdx.x >> 5) * 64 + wave * 16;   // 16 q-blocks of 64 rows

    const unsigned short* qp   = Qb + (size_t)bh * 65536 + (size_t)(q0 >> 4) * 1024 + lane * 8;
    const unsigned short* ksrc = Kb + (size_t)bh * 65536;
    const unsigned short* vsrc = Vt + (size_t)bh * 65536;

    // bpermute byte addresses: pull from quad (2q)&3 / (2q+1)&3 at same l16
    const int sA  = ((((2 * quad) & 3) << 4) + l16) << 2;
    const int sB2 = ((((2 * quad + 1) & 3) << 4) + l16) << 2;

    bf16x8 qf0 = *(const bf16x8*)qp;
    bf16x8 qf1 = *(const bf16x8*)(qp + 512);

    f32x4 o[4];
#pragma unroll
    for (int nf = 0; nf < 4; ++nf) o[nf] = (f32x4){0.f, 0.f, 0.f, 0.f};
    float lp = 0.f;   // per-lane partial column (=query) sum

    // stage K/V tile for keys [j, j+64) into buf
    auto STAGE = [&](int j, int buf) {
        // K-tile: contiguous 4096 shorts
        gl_lds16(ksrc + (size_t)j * 64 + tid * 8,        &Ks[buf][tid * 8]);
        gl_lds16(ksrc + (size_t)j * 64 + 2048 + tid * 8, &Ks[buf][2048 + tid * 8]);
        // V-tile: 8 chunks of 512 shorts; wave w covers chunk w, then w+4
        gl_lds16(vsrc + (size_t)j * 16 + (size_t)(wave >> 1) * 16384
                      + (wave & 1) * 512 + lane * 8,
                 &Vs[buf][wave * 512 + lane * 8]);
        gl_lds16(vsrc + (size_t)j * 16 + (size_t)((wave + 4) >> 1) * 16384
                      + ((wave + 4) & 1) * 512 + lane * 8,
                 &Vs[buf][2048 + wave * 512 + lane * 8]);
    };

    STAGE(0, 0);
    __syncthreads();

    for (int it = 0; it < 16; ++it) {
        const int cur = it & 1;
        if (it + 1 < 16) STAGE((it + 1) * 64, cur ^ 1);
        // ---- S^T tiles: row = key (quad*4+r within tile nf), col = query (l16) ----
        unsigned pk01[4], pk23[4];
#pragma unroll
        for (int nf = 0; nf < 4; ++nf) {
            bf16x8 kc0 = *(const bf16x8*)&Ks[cur][nf * 1024 + lane * 8];
            bf16x8 kc1 = *(const bf16x8*)&Ks[cur][nf * 1024 + 512 + lane * 8];
            f32x4 z = {0.f, 0.f, 0.f, 0.f};
            z = __builtin_amdgcn_mfma_f32_16x16x32_bf16(kc0, qf0, z, 0, 0, 0);
            z = __builtin_amdgcn_mfma_f32_16x16x32_bf16(kc1, qf1, z, 0, 0, 0);
            float p0 = __expf(z[0]);
            float p1 = __expf(z[1]);
            float p2 = __expf(z[2]);
            float p3 = __expf(z[3]);
            lp += (p0 + p1) + (p2 + p3);
            pk01[nf] = pack2(p0, p1);
            pk23[nf] = pack2(p2, p3);
        }
        // ---- register-only C->A transform (validated) ----
        union PU { unsigned d[4]; bf16x8 v; } f0, f1;
        {
            unsigned a0, a1;
            a0 = (unsigned)__builtin_amdgcn_ds_bpermute(sA,  (int)pk01[0]);
            a1 = (unsigned)__builtin_amdgcn_ds_bpermute(sA,  (int)pk01[1]);
            f0.d[0] = (quad < 2) ? a0 : a1;
            a0 = (unsigned)__builtin_amdgcn_ds_bpermute(sA,  (int)pk23[0]);
            a1 = (unsigned)__builtin_amdgcn_ds_bpermute(sA,  (int)pk23[1]);
            f0.d[1] = (quad < 2) ? a0 : a1;
            a0 = (unsigned)__builtin_amdgcn_ds_bpermute(sB2, (int)pk01[0]);
            a1 = (unsigned)__builtin_amdgcn_ds_bpermute(sB2, (int)pk01[1]);
            f0.d[2] = (quad < 2) ? a0 : a1;
            a0 = (unsigned)__builtin_amdgcn_ds_bpermute(sB2, (int)pk23[0]);
            a1 = (unsigned)__builtin_amdgcn_ds_bpermute(sB2, (int)pk23[1]);
            f0.d[3] = (quad < 2) ? a0 : a1;
            a0 = (unsigned)__builtin_amdgcn_ds_bpermute(sA,  (int)pk01[2]);
            a1 = (unsigned)__builtin_amdgcn_ds_bpermute(sA,  (int)pk01[3]);
            f1.d[0] = (quad < 2) ? a0 : a1;
            a0 = (unsigned)__builtin_amdgcn_ds_bpermute(sA,  (int)pk23[2]);
            a1 = (unsigned)__builtin_amdgcn_ds_bpermute(sA,  (int)pk23[3]);
            f1.d[1] = (quad < 2) ? a0 : a1;
            a0 = (unsigned)__builtin_amdgcn_ds_bpermute(sB2, (int)pk01[2]);
            a1 = (unsigned)__builtin_amdgcn_ds_bpermute(sB2, (int)pk01[3]);
            f1.d[2] = (quad < 2) ? a0 : a1;
            a0 = (unsigned)__builtin_amdgcn_ds_bpermute(sB2, (int)pk23[2]);
            a1 = (unsigned)__builtin_amdgcn_ds_bpermute(sB2, (int)pk23[3]);
            f1.d[3] = (quad < 2) ? a0 : a1;
        }
        // ---- O += P.V ----
#pragma unroll
        for (int nf = 0; nf < 4; ++nf) {
            bf16x8 vf0 = *(const bf16x8*)&Vs[cur][nf * 1024 + lane * 8];
            bf16x8 vf1 = *(const bf16x8*)&Vs[cur][nf * 1024 + 512 + lane * 8];
            o[nf] = __builtin_amdgcn_mfma_f32_16x16x32_bf16(f0.v, vf0, o[nf], 0, 0, 0);
            o[nf] = __builtin_amdgcn_mfma_f32_16x16x32_bf16(f1.v, vf1, o[nf], 0, 0, 0);
        }
        __syncthreads();   // drains vmcnt(0): next tile landed, cur reads done
    }

    // ---- per-wave denominators: full sum for query l16, then transpose ----
    float ts = lp;
    ts += __shfl_xor(ts, 16, 64);
    ts += __shfl_xor(ts, 32, 64);
    union { float f; int i; } tsb; tsb.f = ts;
    // ---- write: o[nf][r] = O[q = quad*4+r][d = nf*16+l16] ----
#pragma unroll
    for (int r = 0; r < 4; ++r) {
        union { int i; float f; } dv;
        dv.i = __builtin_amdgcn_ds_bpermute((quad * 20 + r) << 2, tsb.i);
        float inv = 1.0f / dv.f;
        int q = q0 + quad * 4 + r;
#pragma unroll
        for (int nf = 0; nf < 4; ++nf)
            av[((size_t)(b * 1024 + q)) * D + h * 64 + nf * 16 + l16] =
                f2bf(o[nf][r] * inv);
    }
}

// ---------------- classifier ----------------
__global__ __launch_bounds__(256) void cls_kernel(
    const float* __restrict__ x, const float* __restrict__ Wc,
    const float* __restrict__ bc, float* __restrict__ out)
{
    int lane = threadIdx.x & 63;
    int row = blockIdx.x * 4 + (threadIdx.x >> 6);
    const float* xr = x + (size_t)row * D + lane * 8;
    float4 v0 = *(const float4*)xr;
    float4 v1 = *(const float4*)(xr + 4);
    float acc[10];
#pragma unroll
    for (int c = 0; c < 10; ++c) {
        const float* wr = Wc + c * D + lane * 8;
        float4 w0 = *(const float4*)wr;
        float4 w1 = *(const float4*)(wr + 4);
        acc[c] = v0.x*w0.x + v0.y*w0.y + v0.z*w0.z + v0.w*w0.w
               + v1.x*w1.x + v1.y*w1.y + v1.z*w1.z + v1.w*w1.w;
    }
#pragma unroll
    for (int c = 0; c < 10; ++c)
#pragma unroll
        for (int off = 32; off; off >>= 1) acc[c] += __shfl_xor(acc[c], off, 64);
    if (lane == 0) {
#pragma unroll
        for (int c = 0; c < 10; ++c) out[(size_t)row * 10 + c] = acc[c] + bc[c];
    }
}

extern "C" void kernel_launch(void* const* d_in, const int* in_sizes, int n_in,
                              void* d_out, int out_size, void* d_ws, size_t ws_size,
                              hipStream_t stream)
{
    const int*   tokens = (const int*)  d_in[0];
    const float* emb    = (const float*)d_in[1];
    const float* Wq     = (const float*)d_in[2];
    const float* bq     = (const float*)d_in[3];
    const float* Wkv    = (const float*)d_in[4];
    const float* bkv    = (const float*)d_in[5];
    const float* Wo     = (const float*)d_in[6];
    const float* bo     = (const float*)d_in[7];
    const float* ln1g   = (const float*)d_in[8];
    const float* ln1b   = (const float*)d_in[9];
    const float* W1     = (const float*)d_in[10];
    const float* b1     = (const float*)d_in[11];
    const float* W2     = (const float*)d_in[12];
    const float* b2     = (const float*)d_in[13];
    const float* ln2g   = (const float*)d_in[14];
    const float* ln2b   = (const float*)d_in[15];
    const float* Wc     = (const float*)d_in[16];
    const float* bc     = (const float*)d_in[17];
    float* out = (float*)d_out;

    // workspace (~64 MB; harness poisons >=268MB per fillBuffer WRITE_SIZE):
    // x fp32 8MB | hb bf16 4MB | Qb 4 | Kb 4 | Vt 4 | avb 4 (f1b aliases Qb..)
    // | wl bf16 6x6MB = 36MB | wbias fp32 36KB
    float* x  = (float*)d_ws;
    unsigned short* hb  = (unsigned short*)(x + (size_t)MTOK * D);
    unsigned short* Qb  = hb  + (size_t)MTOK * D;
    unsigned short* Kb  = Qb  + (size_t)32 * 1024 * 64;
    unsigned short* Vt  = Kb  + (size_t)32 * 1024 * 64;
    unsigned short* avb = Vt  + (size_t)32 * 1024 * 64;
    unsigned short* f1b = Qb;                              // [4096][2048] bf16 = 16 MB
    unsigned short* wl  = avb + (size_t)32 * 1024 * 64;    // all-layer bf16 weights (36 MB)
    float* wbias = (float*)(wl + (size_t)6 * 3145728);     // combined [bq;bkv] x 6 (36 KB)

    // per-layer wl layout: [Wq;Wkv] contiguous 1536x512, then Wo, W1, W2
    const size_t oWo = 786432, oW1 = 1048576, oW2 = 2097152, LW = 3145728;

    prep_kernel<<<11265, 256, 0, stream>>>(
        tokens, emb, Wq, Wkv, Wo, W1, W2, bq, bkv, wl, wbias, x);

    for (int l = 0; l < NLAYER; ++l) {
        const unsigned short* wll = wl + (size_t)l * LW;
        ln_kernel<<<MTOK / 4, 256, 0, stream>>>(x, ln1g + l * D, ln1b + l * D, hb);
        gemm_bf16<2,128,64,64><<<dim3(24, 32), 256, 0, stream>>>(
            hb, wll, wbias + l * 1536, nullptr, Qb, Kb, Vt, MTOK, 1536, 512);
        attn_mfma<<<512, 256, 0, stream>>>(Qb, Kb, Vt, avb);
        gemm_bf16<0,64,64,128><<<dim3(8, 64), 256, 0, stream>>>(
            avb, wll + oWo, bo + l * D, x, x, nullptr, nullptr, MTOK, D, D);
        ln_kernel<<<MTOK / 4, 256, 0, stream>>>(x, ln2g + l * D, ln2b + l * D, hb);
        gemm_bf16<1,128,128,64><<<dim3(16, 32), 256, 0, stream>>>(
            hb, wll + oW1, b1 + l * 4 * D, nullptr, f1b, nullptr, nullptr, MTOK, 4 * D, D);
        gemm_bf16<0,64,64,128><<<dim3(8, 64), 256, 0, stream>>>(
            f1b, wll + oW2, b2 + l * D, x, x, nullptr, nullptr, MTOK, D, 4 * D);
    }

    cls_kernel<<<MTOK / 4, 256, 0, stream>>>(x, Wc, bc, out);
}

// Round 13
// 686.121 us; speedup vs baseline: 1.0279x; 1.0022x over previous
//
#include <hip/hip_runtime.h>
#include <math.h>

#define D 512
#define HEADS 8
#define NLAYER 6
#define LSEQ 1024
#define BATCH 4
#define DKH 64
#define MTOK (BATCH*LSEQ)   // 4096 tokens
#define EPS 1e-5f
#define EMB_SCALE 22.627416997969522f  // sqrt(512)
#define INV_SCALE 0.125f               // 1/sqrt(64)

typedef __attribute__((ext_vector_type(8))) __bf16 bf16x8;
typedef __attribute__((ext_vector_type(4))) float f32x4;

__device__ __forceinline__ unsigned short f2bf(float x) {
    union { float f; unsigned u; } v; v.f = x;
    unsigned r = (v.u + 0x7FFFu + ((v.u >> 16) & 1u)) >> 16;
    return (unsigned short)r;
}
__device__ __forceinline__ unsigned pack2(float a, float b) {
    return (unsigned)f2bf(a) | ((unsigned)f2bf(b) << 16);
}
__device__ __forceinline__ void gl_lds16(const unsigned short* g, unsigned short* l) {
    __builtin_amdgcn_global_load_lds(
        (const __attribute__((address_space(1))) unsigned*)g,
        (__attribute__((address_space(3))) unsigned*)l, 16, 0, 0);
}
// asm 16B global load (attn): volatile asm cannot be sunk -> pipeline holds.
__device__ __forceinline__ void gload16(bf16x8& d, const unsigned short* p) {
    asm volatile("global_load_dwordx4 %0, %1, off" : "=v"(d) : "v"(p));
}

// ---------------- prep: ALL-layer weight fp32->bf16 + biases + embedding ----
__global__ __launch_bounds__(256) void prep_kernel(
    const int* __restrict__ tokens, const float* __restrict__ emb,
    const float* __restrict__ Wq, const float* __restrict__ Wkv,
    const float* __restrict__ Wo, const float* __restrict__ W1,
    const float* __restrict__ W2, const float* __restrict__ bq,
    const float* __restrict__ bkv, unsigned short* __restrict__ wl,
    float* __restrict__ wbias, float* __restrict__ x)
{
    const int bid = blockIdx.x;
    if (bid < 9216) {                       // weight conversion, 6 layers
        const int l = bid / 1536;
        const int e = (bid - l * 1536) * 2048 + threadIdx.x * 8;
        const float* src;
        if      (e < 262144)  src = Wq  + (size_t)l * 262144  + e;
        else if (e < 786432)  src = Wkv + (size_t)l * 524288  + (e - 262144);
        else if (e < 1048576) src = Wo  + (size_t)l * 262144  + (e - 786432);
        else if (e < 2097152) src = W1  + (size_t)l * 1048576 + (e - 1048576);
        else                  src = W2  + (size_t)l * 1048576 + (e - 2097152);
        float4 a = *(const float4*)src;
        float4 b = *(const float4*)(src + 4);
        uint4 o;
        o.x = pack2(a.x, a.y); o.y = pack2(a.z, a.w);
        o.z = pack2(b.x, b.y); o.w = pack2(b.z, b.w);
        *(uint4*)(wl + (size_t)l * 3145728 + e) = o;
    } else if (bid == 9216) {               // combined QKV biases, 6 layers
        for (int i = threadIdx.x; i < 9216; i += 256) {
            int l = i / 1536, j = i - l * 1536;
            wbias[i] = (j < 512) ? bq[l * 512 + j] : bkv[l * 1024 + (j - 512)];
        }
    } else {                                // embedding + positional encoding
        int row = (bid - 9217) * 2 + (threadIdx.x >> 7);
        int pos = row & (LSEQ - 1);
        int tok = tokens[row];
        int c = (threadIdx.x & 127) * 4;
        float4 e = *(const float4*)(emb + (size_t)tok * D + c);
        float o[4] = {e.x, e.y, e.z, e.w};
#pragma unroll
        for (int i = 0; i < 4; ++i) {
            int col = c + i;
            int ii = col & ~1;
            float dv = expf(-(float)ii * (9.210340371976184f / (float)D));
            float a = (float)pos * dv;
            float pe = (col & 1) ? cosf(a) : sinf(a);
            o[i] = o[i] * EMB_SCALE + pe;
        }
        float4 r; r.x = o[0]; r.y = o[1]; r.z = o[2]; r.w = o[3];
        *(float4*)(x + (size_t)row * D + c) = r;
    }
}

// ---------------- layernorm fp32 -> bf16: one wave per row ----------------
__global__ __launch_bounds__(256) void ln_kernel(
    const float* __restrict__ x, const float* __restrict__ g,
    const float* __restrict__ b, unsigned short* __restrict__ h)
{
    int lane = threadIdx.x & 63;
    int row = blockIdx.x * 4 + (threadIdx.x >> 6);
    const float* xr = x + (size_t)row * D + lane * 8;
    float4 v0 = *(const float4*)(xr);
    float4 v1 = *(const float4*)(xr + 4);
    float s = v0.x + v0.y + v0.z + v0.w + v1.x + v1.y + v1.z + v1.w;
#pragma unroll
    for (int off = 32; off; off >>= 1) s += __shfl_xor(s, off, 64);
    float m = s * (1.0f / D);
    float d0 = v0.x - m, d1 = v0.y - m, d2 = v0.z - m, d3 = v0.w - m;
    float d4 = v1.x - m, d5 = v1.y - m, d6 = v1.z - m, d7 = v1.w - m;
    float ss = d0*d0 + d1*d1 + d2*d2 + d3*d3 + d4*d4 + d5*d5 + d6*d6 + d7*d7;
#pragma unroll
    for (int off = 32; off; off >>= 1) ss += __shfl_xor(ss, off, 64);
    float inv = rsqrtf(ss * (1.0f / D) + EPS);
    const float* gp = g + lane * 8;
    const float* bp = b + lane * 8;
    float4 g0 = *(const float4*)(gp), g1 = *(const float4*)(gp + 4);
    float4 b0 = *(const float4*)(bp), b1 = *(const float4*)(bp + 4);
    uint4 o;
    o.x = pack2(d0 * inv * g0.x + b0.x, d1 * inv * g0.y + b0.y);
    o.y = pack2(d2 * inv * g0.z + b0.z, d3 * inv * g0.w + b0.w);
    o.z = pack2(d4 * inv * g1.x + b1.x, d5 * inv * g1.y + b1.y);
    o.w = pack2(d6 * inv * g1.z + b1.z, d7 * inv * g1.w + b1.w);
    *(uint4*)(h + (size_t)row * D + lane * 8) = o;
}

// ---------------- bf16 MFMA GEMM: acc = A(bf16 MxK) @ W(bf16 NxK)^T ----------------
// 2-phase double-buffered pipeline, XOR-swizzled LDS (R3/R4/R9/R10 validated).
// R13 = exact R10 restore (best measured 681us). R11/R12 deviations all
// measured worse -> reverted. Config: QKV BN=64 (768 blocks = 3/CU),
// Wo/FFN2 BM=64 BN=64 BK=128 (512 = 2/CU), FFN1 BM=128 BN=128 BK=64.
// OMODE 0: C fp32 [M][N] = acc + bias + X (residual)
// OMODE 1: C bf16 [M][N] = relu(acc + bias)
// OMODE 2: fused QKV (N=1536), fragment-linear outputs for attn.
template<int OMODE, int BM, int BN, int BK>
__global__ __launch_bounds__(256) void gemm_bf16(
    const unsigned short* __restrict__ A, const unsigned short* __restrict__ W,
    const float* __restrict__ bias, const float* __restrict__ X,
    void* __restrict__ C, void* __restrict__ C2, void* __restrict__ C3,
    int M, int N, int K)
{
    constexpr int WM = BM / 64;        // 2 or 1
    constexpr int WN = 4 / WM;         // 2 or 4
    constexpr int NI = BN / (WN * 16); // 16-col frags per wave
    constexpr int CPB = BK / 8;        // 8-short chunks per row
    constexpr int RPP = 2048 / BK;     // rows covered per 256-thread pass
    __shared__ __align__(16) unsigned short As[2][BM * BK];
    __shared__ __align__(16) unsigned short Bs[2][BN * BK];
    const int tid = threadIdx.x;
    const int wave = tid >> 6, lane = tid & 63;
    const int quad = lane >> 4, l16 = lane & 15;
    const int wm = wave / WN, wn = wave % WN;
    const int bm = blockIdx.y * BM, bn = blockIdx.x * BN;

    // staging: thread covers row rS of each RPP-row group, chunk ch (8 shorts).
    // source column chunk is XOR-swizzled so linear LDS holds swizzled data:
    // LDS[r][c] = G[r][c ^ (r&7)]; reads apply the same XOR.
    const int rS  = tid / CPB;
    const int ch  = tid % CPB;
    const int csw = ((ch ^ (rS & 7)) << 3);
    const unsigned short* Asrc = A + (size_t)(bm + rS) * K + csw;
    const unsigned short* Bsrc = W + (size_t)(bn + rS) * K + csw;

    f32x4 acc[4][NI];
#pragma unroll
    for (int mi = 0; mi < 4; ++mi)
#pragma unroll
        for (int ni = 0; ni < NI; ++ni) acc[mi][ni] = (f32x4){0.f, 0.f, 0.f, 0.f};

    const int nt = K / BK;

    // prologue: stage tile 0
#pragma unroll
    for (int i = 0; i < BM / RPP; ++i)
        gl_lds16(Asrc + (size_t)(i * RPP) * K, &As[0][i * 2048 + tid * 8]);
#pragma unroll
    for (int i = 0; i < BN / RPP; ++i)
        gl_lds16(Bsrc + (size_t)(i * RPP) * K, &Bs[0][i * 2048 + tid * 8]);
    __syncthreads();

    for (int t = 0; t < nt; ++t) {
        const int cur = t & 1;
        if (t + 1 < nt) {
            const int k0 = (t + 1) * BK;
#pragma unroll
            for (int i = 0; i < BM / RPP; ++i)
                gl_lds16(Asrc + (size_t)(i * RPP) * K + k0, &As[cur ^ 1][i * 2048 + tid * 8]);
#pragma unroll
            for (int i = 0; i < BN / RPP; ++i)
                gl_lds16(Bsrc + (size_t)(i * RPP) * K + k0, &Bs[cur ^ 1][i * 2048 + tid * 8]);
        }
#pragma unroll
        for (int kc = 0; kc < BK / 32; ++kc) {
            const int gch = (kc << 2) | quad;   // global col chunk this quad wants
            bf16x8 af[4], bfr[NI];
#pragma unroll
            for (int mi = 0; mi < 4; ++mi) {
                const int ra = wm * 64 + mi * 16 + l16;
                af[mi] = *(const bf16x8*)&As[cur][ra * BK + ((gch ^ (ra & 7)) << 3)];
            }
#pragma unroll
            for (int ni = 0; ni < NI; ++ni) {
                const int rb = wn * (BN / WN) + ni * 16 + l16;
                bfr[ni] = *(const bf16x8*)&Bs[cur][rb * BK + ((gch ^ (rb & 7)) << 3)];
            }
#pragma unroll
            for (int mi = 0; mi < 4; ++mi)
#pragma unroll
                for (int ni = 0; ni < NI; ++ni)
                    acc[mi][ni] = __builtin_amdgcn_mfma_f32_16x16x32_bf16(
                        af[mi], bfr[ni], acc[mi][ni], 0, 0, 0);
        }
        __syncthreads();   // drains vmcnt(0): next tile landed, cur reads done
    }

    const int er = bm + wm * 64;
    const int ec = bn + wn * (BN / WN);

    if (OMODE == 0) {
        float* Cf = (float*)C;
#pragma unroll
        for (int ni = 0; ni < NI; ++ni) {
            int c = ec + ni * 16 + l16;
            float bv = bias[c];
#pragma unroll
            for (int mi = 0; mi < 4; ++mi)
#pragma unroll
                for (int r = 0; r < 4; ++r) {
                    int m = er + mi * 16 + quad * 4 + r;
                    Cf[(size_t)m * N + c] = acc[mi][ni][r] + bv + X[(size_t)m * N + c];
                }
        }
    } else if (OMODE == 1) {
        unsigned short* Cb = (unsigned short*)C;
#pragma unroll
        for (int ni = 0; ni < NI; ++ni) {
            int c = ec + ni * 16 + l16;
            float bv = bias[c];
#pragma unroll
            for (int mi = 0; mi < 4; ++mi)
#pragma unroll
                for (int r = 0; r < 4; ++r) {
                    int m = er + mi * 16 + quad * 4 + r;
                    Cb[(size_t)m * N + c] = f2bf(fmaxf(acc[mi][ni][r] + bv, 0.f));
                }
        }
    } else {
        if (bn < 512) {            // Q (scaled), fragment-linear
            unsigned short* Qp = (unsigned short*)C;
#pragma unroll
            for (int ni = 0; ni < NI; ++ni) {
                int c = ec + ni * 16 + l16;
                float bv = bias[c];
                int hh = c >> 6, dd = c & 63;
                size_t cbase = (size_t)(dd >> 5) * 512 + (size_t)((dd >> 3) & 3) * 128 + (dd & 7);
#pragma unroll
                for (int mi = 0; mi < 4; ++mi)
#pragma unroll
                    for (int r = 0; r < 4; ++r) {
                        int m = er + mi * 16 + quad * 4 + r;
                        int b = m >> 10, t = m & 1023;
                        Qp[(size_t)(b * 8 + hh) * 65536 + (size_t)(t >> 4) * 1024
                           + cbase + (size_t)(t & 15) * 8] =
                            f2bf((acc[mi][ni][r] + bv) * INV_SCALE);
                    }
            }
        } else if (bn < 1024) {    // K, fragment-linear
            unsigned short* Kp = (unsigned short*)C2;
#pragma unroll
            for (int ni = 0; ni < NI; ++ni) {
                int c = ec + ni * 16 + l16;
                float bv = bias[c];
                int c2 = c - 512;
                int hh = c2 >> 6, dd = c2 & 63;
                size_t cbase = (size_t)(dd >> 5) * 512 + (size_t)((dd >> 3) & 3) * 128 + (dd & 7);
#pragma unroll
                for (int mi = 0; mi < 4; ++mi)
#pragma unroll
                    for (int r = 0; r < 4; ++r) {
                        int m = er + mi * 16 + quad * 4 + r;
                        int b = m >> 10, t = m & 1023;
                        Kp[(size_t)(b * 8 + hh) * 65536 + (size_t)(t >> 4) * 1024
                           + cbase + (size_t)(t & 15) * 8] =
                            f2bf(acc[mi][ni][r] + bv);
                    }
            }
        } else {                   // V, fragment-linear (transposed consumption)
            unsigned short* Vp = (unsigned short*)C3;
#pragma unroll
            for (int ni = 0; ni < NI; ++ni) {
                int c = ec + ni * 16 + l16;
                float bv = bias[c];
                int c2 = c - 1024;
                int hh = c2 >> 6, dd = c2 & 63;
                size_t dbase = (size_t)(dd >> 4) * 16384 + (size_t)(dd & 15) * 8;
#pragma unroll
                for (int mi = 0; mi < 4; ++mi) {
                    int t0 = er + mi * 16 + quad * 4;
                    int b = t0 >> 10, tt = t0 & 1023;
                    ushort4 o;
                    o.x = f2bf(acc[mi][ni][0] + bv);
                    o.y = f2bf(acc[mi][ni][1] + bv);
                    o.z = f2bf(acc[mi][ni][2] + bv);
                    o.w = f2bf(acc[mi][ni][3] + bv);
                    *(ushort4*)(Vp + (size_t)(b * 8 + hh) * 65536 + dbase
                                + (size_t)(tt >> 5) * 512
                                + (size_t)((tt >> 3) & 3) * 128 + (tt & 7)) = o;
                }
            }
        }
    }
}

// ---------------- flash attention: split-K, QROWS=32 per block (R4/R10) ----
// Fragment-linear layouts + asm-pinned double-buffered private loads.
__global__ __launch_bounds__(256, 1) void attn_mfma(
    const unsigned short* __restrict__ Qb, const unsigned short* __restrict__ Kb,
    const unsigned short* __restrict__ Vt, unsigned short* __restrict__ av)
{
    __shared__ float Ol[4][32][68];   // [wave][q][d] fp32 partial O (+pad)
    __shared__ float Ls[4][32];       // [wave][q] partial denominators
    const int tid = threadIdx.x;
    const int wave = tid >> 6, lane = tid & 63;
    const int quad = lane >> 4, l16 = lane & 15;
    const int bh = blockIdx.x & 31;          // xcd = bh % 8 -> K/V L2-resident per XCD
    const int b = bh >> 3, h = bh & 7;
    const int q0 = (blockIdx.x >> 5) * 32;   // 32 q-tiles of 32 rows

    const unsigned short* qp = Qb + (size_t)bh * 65536 + (size_t)(q0 >> 4) * 1024 + lane * 8;
    const unsigned short* kbase = Kb + (size_t)bh * 65536 + lane * 8;
    const unsigned short* vbase = Vt + (size_t)bh * 65536 + lane * 8;

    // bpermute byte addresses: pull from quad (2q)&3 / (2q+1)&3 at same l16
    const int sA  = ((((2 * quad) & 3) << 4) + l16) << 2;
    const int sB2 = ((((2 * quad + 1) & 3) << 4) + l16) << 2;

    f32x4 o[2][4];
#pragma unroll
    for (int qs = 0; qs < 2; ++qs)
#pragma unroll
        for (int nf = 0; nf < 4; ++nf) o[qs][nf] = (f32x4){0.f, 0.f, 0.f, 0.f};
    float lp[2] = {0.f, 0.f};   // per-lane partial column (=query) sums

    const int j0 = wave * 256;

    // ---- prologue: issue Q (4) + buffer0 K/V (16) loads; 20 in flight ----
    bf16x8 qf[2][2];
    gload16(qf[0][0], qp);
    gload16(qf[0][1], qp + 512);
    gload16(qf[1][0], qp + 1024);
    gload16(qf[1][1], qp + 1536);

    bf16x8 kc[2][8], vf[2][8];
#pragma unroll
    for (int nf = 0; nf < 4; ++nf) {
        gload16(kc[0][2 * nf],     kbase + (size_t)j0 * 64 + nf * 1024);
        gload16(kc[0][2 * nf + 1], kbase + (size_t)j0 * 64 + nf * 1024 + 512);
        gload16(vf[0][2 * nf],     vbase + (size_t)j0 * 16 + nf * 16384);
        gload16(vf[0][2 * nf + 1], vbase + (size_t)j0 * 16 + nf * 16384 + 512);
    }

#pragma unroll
    for (int it = 0; it < 4; ++it) {
        const int cur = it & 1, nxt = cur ^ 1;
        // ---- issue next tile's 16 loads BEFORE waiting on current ----
        if (it < 3) {
            const int jn = j0 + (it + 1) * 64;
#pragma unroll
            for (int nf = 0; nf < 4; ++nf) {
                gload16(kc[nxt][2 * nf],     kbase + (size_t)jn * 64 + nf * 1024);
                gload16(kc[nxt][2 * nf + 1], kbase + (size_t)jn * 64 + nf * 1024 + 512);
                gload16(vf[nxt][2 * nf],     vbase + (size_t)jn * 16 + nf * 16384);
                gload16(vf[nxt][2 * nf + 1], vbase + (size_t)jn * 16 + nf * 16384 + 512);
            }
        }
        // ---- counted wait: current buffer (+Q at it=0) done, next 16 in flight ----
        if (it < 3) asm volatile("s_waitcnt vmcnt(16)" ::: "memory");
        else        asm volatile("s_waitcnt vmcnt(0)"  ::: "memory");
        __builtin_amdgcn_sched_barrier(0);
        // ---- S^T tiles (row=key, col=query), exp, pack — per (nf, qs) ----
        unsigned pk01[2][4], pk23[2][4];
#pragma unroll
        for (int nf = 0; nf < 4; ++nf)
#pragma unroll
            for (int qs = 0; qs < 2; ++qs) {
                f32x4 z = {0.f, 0.f, 0.f, 0.f};
                z = __builtin_amdgcn_mfma_f32_16x16x32_bf16(kc[cur][2 * nf], qf[qs][0], z, 0, 0, 0);
                z = __builtin_amdgcn_mfma_f32_16x16x32_bf16(kc[cur][2 * nf + 1], qf[qs][1], z, 0, 0, 0);
                float p0 = __expf(z[0]);
                float p1 = __expf(z[1]);
                float p2 = __expf(z[2]);
                float p3 = __expf(z[3]);
                lp[qs] += (p0 + p1) + (p2 + p3);
                pk01[qs][nf] = pack2(p0, p1);
                pk23[qs][nf] = pack2(p2, p3);
            }
        // ---- register-only C->A transform (validated), per q-subtile ----
#pragma unroll
        for (int qs = 0; qs < 2; ++qs) {
            union PU { unsigned d[4]; bf16x8 v; } f0, f1;
            unsigned a0, a1;
            a0 = (unsigned)__builtin_amdgcn_ds_bpermute(sA,  (int)pk01[qs][0]);
            a1 = (unsigned)__builtin_amdgcn_ds_bpermute(sA,  (int)pk01[qs][1]);
            f0.d[0] = (quad < 2) ? a0 : a1;
            a0 = (unsigned)__builtin_amdgcn_ds_bpermute(sA,  (int)pk23[qs][0]);
            a1 = (unsigned)__builtin_amdgcn_ds_bpermute(sA,  (int)pk23[qs][1]);
            f0.d[1] = (quad < 2) ? a0 : a1;
            a0 = (unsigned)__builtin_amdgcn_ds_bpermute(sB2, (int)pk01[qs][0]);
            a1 = (unsigned)__builtin_amdgcn_ds_bpermute(sB2, (int)pk01[qs][1]);
            f0.d[2] = (quad < 2) ? a0 : a1;
            a0 = (unsigned)__builtin_amdgcn_ds_bpermute(sB2, (int)pk23[qs][0]);
            a1 = (unsigned)__builtin_amdgcn_ds_bpermute(sB2, (int)pk23[qs][1]);
            f0.d[3] = (quad < 2) ? a0 : a1;
            a0 = (unsigned)__builtin_amdgcn_ds_bpermute(sA,  (int)pk01[qs][2]);
            a1 = (unsigned)__builtin_amdgcn_ds_bpermute(sA,  (int)pk01[qs][3]);
            f1.d[0] = (quad < 2) ? a0 : a1;
            a0 = (unsigned)__builtin_amdgcn_ds_bpermute(sA,  (int)pk23[qs][2]);
            a1 = (unsigned)__builtin_amdgcn_ds_bpermute(sA,  (int)pk23[qs][3]);
            f1.d[1] = (quad < 2) ? a0 : a1;
            a0 = (unsigned)__builtin_amdgcn_ds_bpermute(sB2, (int)pk01[qs][2]);
            a1 = (unsigned)__builtin_amdgcn_ds_bpermute(sB2, (int)pk01[qs][3]);
            f1.d[2] = (quad < 2) ? a0 : a1;
            a0 = (unsigned)__builtin_amdgcn_ds_bpermute(sB2, (int)pk23[qs][2]);
            a1 = (unsigned)__builtin_amdgcn_ds_bpermute(sB2, (int)pk23[qs][3]);
            f1.d[3] = (quad < 2) ? a0 : a1;
            // ---- O += P.V ----
#pragma unroll
            for (int nf = 0; nf < 4; ++nf) {
                o[qs][nf] = __builtin_amdgcn_mfma_f32_16x16x32_bf16(f0.v, vf[cur][2 * nf], o[qs][nf], 0, 0, 0);
                o[qs][nf] = __builtin_amdgcn_mfma_f32_16x16x32_bf16(f1.v, vf[cur][2 * nf + 1], o[qs][nf], 0, 0, 0);
            }
        }
    }
    // ---- write per-wave partials to LDS ----
#pragma unroll
    for (int qs = 0; qs < 2; ++qs)
#pragma unroll
        for (int nf = 0; nf < 4; ++nf)
#pragma unroll
            for (int r = 0; r < 4; ++r)
                Ol[wave][qs * 16 + quad * 4 + r][nf * 16 + l16] = o[qs][nf][r];
#pragma unroll
    for (int qs = 0; qs < 2; ++qs) {
        float ts = lp[qs];
        ts += __shfl_xor(ts, 16, 64);
        ts += __shfl_xor(ts, 32, 64);
        if (quad == 0) Ls[wave][qs * 16 + l16] = ts;
    }
    __syncthreads();
    // ---- combine: wave w handles d-frag nf=w, 32 q rows ----
#pragma unroll
    for (int half = 0; half < 2; ++half)
#pragma unroll
        for (int r = 0; r < 4; ++r) {
            int qq = half * 16 + quad * 4 + r;
            float denom = Ls[0][qq] + Ls[1][qq] + Ls[2][qq] + Ls[3][qq];
            float v = Ol[0][qq][wave * 16 + l16] + Ol[1][qq][wave * 16 + l16]
                    + Ol[2][qq][wave * 16 + l16] + Ol[3][qq][wave * 16 + l16];
            int q = q0 + qq;
            av[((size_t)(b * 1024 + q)) * D + h * 64 + wave * 16 + l16] =
                f2bf(v / denom);
        }
}

// ---------------- classifier ----------------
__global__ __launch_bounds__(256) void cls_kernel(
    const float* __restrict__ x, const float* __restrict__ Wc,
    const float* __restrict__ bc, float* __restrict__ out)
{
    int lane = threadIdx.x & 63;
    int row = blockIdx.x * 4 + (threadIdx.x >> 6);
    const float* xr = x + (size_t)row * D + lane * 8;
    float4 v0 = *(const float4*)xr;
    float4 v1 = *(const float4*)(xr + 4);
    float acc[10];
#pragma unroll
    for (int c = 0; c < 10; ++c) {
        const float* wr = Wc + c * D + lane * 8;
        float4 w0 = *(const float4*)wr;
        float4 w1 = *(const float4*)(wr + 4);
        acc[c] = v0.x*w0.x + v0.y*w0.y + v0.z*w0.z + v0.w*w0.w
               + v1.x*w1.x + v1.y*w1.y + v1.z*w1.z + v1.w*w1.w;
    }
#pragma unroll
    for (int c = 0; c < 10; ++c)
#pragma unroll
        for (int off = 32; off; off >>= 1) acc[c] += __shfl_xor(acc[c], off, 64);
    if (lane == 0) {
#pragma unroll
        for (int c = 0; c < 10; ++c) out[(size_t)row * 10 + c] = acc[c] + bc[c];
    }
}

extern "C" void kernel_launch(void* const* d_in, const int* in_sizes, int n_in,
                              void* d_out, int out_size, void* d_ws, size_t ws_size,
                              hipStream_t stream)
{
    const int*   tokens = (const int*)  d_in[0];
    const float* emb    = (const float*)d_in[1];
    const float* Wq     = (const float*)d_in[2];
    const float* bq     = (const float*)d_in[3];
    const float* Wkv    = (const float*)d_in[4];
    const float* bkv    = (const float*)d_in[5];
    const float* Wo     = (const float*)d_in[6];
    const float* bo     = (const float*)d_in[7];
    const float* ln1g   = (const float*)d_in[8];
    const float* ln1b   = (const float*)d_in[9];
    const float* W1     = (const float*)d_in[10];
    const float* b1     = (const float*)d_in[11];
    const float* W2     = (const float*)d_in[12];
    const float* b2     = (const float*)d_in[13];
    const float* ln2g   = (const float*)d_in[14];
    const float* ln2b   = (const float*)d_in[15];
    const float* Wc     = (const float*)d_in[16];
    const float* bc     = (const float*)d_in[17];
    float* out = (float*)d_out;

    // workspace (~64 MB; harness poisons >=268MB per fillBuffer WRITE_SIZE):
    // x fp32 8MB | hb bf16 4MB | Qb 4 | Kb 4 | Vt 4 | avb 4 (f1b aliases Qb..)
    // | wl bf16 6x6MB = 36MB | wbias fp32 36KB
    float* x  = (float*)d_ws;
    unsigned short* hb  = (unsigned short*)(x + (size_t)MTOK * D);
    unsigned short* Qb  = hb  + (size_t)MTOK * D;
    unsigned short* Kb  = Qb  + (size_t)32 * 1024 * 64;
    unsigned short* Vt  = Kb  + (size_t)32 * 1024 * 64;
    unsigned short* avb = Vt  + (size_t)32 * 1024 * 64;
    unsigned short* f1b = Qb;                              // [4096][2048] bf16 = 16 MB
    unsigned short* wl  = avb + (size_t)32 * 1024 * 64;    // all-layer bf16 weights (36 MB)
    float* wbias = (float*)(wl + (size_t)6 * 3145728);     // combined [bq;bkv] x 6 (36 KB)

    // per-layer wl layout: [Wq;Wkv] contiguous 1536x512, then Wo, W1, W2
    const size_t oWo = 786432, oW1 = 1048576, oW2 = 2097152, LW = 3145728;

    prep_kernel<<<11265, 256, 0, stream>>>(
        tokens, emb, Wq, Wkv, Wo, W1, W2, bq, bkv, wl, wbias, x);

    for (int l = 0; l < NLAYER; ++l) {
        const unsigned short* wll = wl + (size_t)l * LW;
        ln_kernel<<<MTOK / 4, 256, 0, stream>>>(x, ln1g + l * D, ln1b + l * D, hb);
        gemm_bf16<2,128,64,64><<<dim3(24, 32), 256, 0, stream>>>(
            hb, wll, wbias + l * 1536, nullptr, Qb, Kb, Vt, MTOK, 1536, 512);
        attn_mfma<<<1024, 256, 0, stream>>>(Qb, Kb, Vt, avb);
        gemm_bf16<0,64,64,128><<<dim3(8, 64), 256, 0, stream>>>(
            avb, wll + oWo, bo + l * D, x, x, nullptr, nullptr, MTOK, D, D);
        ln_kernel<<<MTOK / 4, 256, 0, stream>>>(x, ln2g + l * D, ln2b + l * D, hb);
        gemm_bf16<1,128,128,64><<<dim3(16, 32), 256, 0, stream>>>(
            hb, wll + oW1, b1 + l * 4 * D, nullptr, f1b, nullptr, nullptr, MTOK, 4 * D, D);
        gemm_bf16<0,64,64,128><<<dim3(8, 64), 256, 0, stream>>>(
            f1b, wll + oW2, b2 + l * D, x, x, nullptr, nullptr, MTOK, D, 4 * D);
    }

    cls_kernel<<<MTOK / 4, 256, 0, stream>>>(x, Wc, bc, out);
}